// Round 2
// baseline (148.053 us; speedup 1.0000x reference)
//
#include <hip/hip_runtime.h>

// VQ quantizer: z [8,8,16,64,64] f32, codebook [512,8] f32
// outputs concat: z_q_st (4194304 f32) | vq_loss (1 f32) | idx (524288 f32-valued)
//
// R16: 2 points per thread (BLK=256, 512 pts/block, grid 1024 unchanged).
// R15 post-mortem: LDS was NOT the residency cap (occupancy 35% unchanged
// after -33KB LDS). VALUBusy 37% => ~3300 VALU instr/wave, issue floor 22us,
// measured 61us => issue DENSITY is the bottleneck (dep chains: 1 load ->
// 4 MFMA -> 16 serial mins, long shuffle butterflies, ~4 waves/SIMD).
// Fix: fatter waves. Per tile ONE bfrag load feeds 8 independent MFMAs +
// 32 independent mins (two point sets); B loads + loop overhead halve; the
// two butterflies / PUSH streams interleave. launch_bounds(256,2): no spills.
// Numerics: identical validated chains (R6-R15, absmax 0). Only delta: eps
// uses max z2 over 128 points (was 64) -> eps only grows -> rescue guarantee
// (candidate set contains np argmin) preserved; extras resolved np-exactly.

#define NPTS      524288      // 8*16*64*64
#define KCODES    512
#define DDIM      8
#define CH_STRIDE 65536       // T*H*W
#define B_STRIDE  524288      // D*T*H*W
#define BLK       256         // threads per block
#define NWAVES    4
#define PPB       512         // points per block (2 per thread)
#define NTILES    32          // 512 codes / 16
#define CMAX      4
#define NLOSS     64          // loss accumulation slots
#define FLT_BIG   3.402823466e+38f

typedef short bf8 __attribute__((ext_vector_type(8)));   // 8 bf16 (4 VGPRs)
typedef float f4  __attribute__((ext_vector_type(4)));   // fp32 accum

__device__ __forceinline__ unsigned short f2bf(float f) {   // RNE f32->bf16
    unsigned u = __float_as_uint(f);
    unsigned r = u + 0x7fffu + ((u >> 16) & 1u);
    return (unsigned short)(r >> 16);
}
__device__ __forceinline__ float bf2f(unsigned short h) {
    return __uint_as_float(((unsigned)h) << 16);
}

// numpy pairwise-sum tree for n=8 (validated absmax 0, R1-R15)
__device__ __forceinline__ float np_sumsq8(const float* x) {
    float p0 = __fmul_rn(x[0], x[0]);
    float p1 = __fmul_rn(x[1], x[1]);
    float p2 = __fmul_rn(x[2], x[2]);
    float p3 = __fmul_rn(x[3], x[3]);
    float p4 = __fmul_rn(x[4], x[4]);
    float p5 = __fmul_rn(x[5], x[5]);
    float p6 = __fmul_rn(x[6], x[6]);
    float p7 = __fmul_rn(x[7], x[7]);
    return __fadd_rn(__fadd_rn(__fadd_rn(p0, p1), __fadd_rn(p2, p3)),
                     __fadd_rn(__fadd_rn(p4, p5), __fadd_rn(p6, p7)));
}

// np-exact distance (identical rounding chain, absmax-0 validated)
__device__ __forceinline__ float np_dist(const float* __restrict__ cb,
                                         const float* __restrict__ e2f,
                                         int k, const float* zv, float z2) {
    const float* c = cb + (size_t)k * DDIM;
    float ze = 0.0f;
    #pragma unroll
    for (int j = 0; j < DDIM; ++j) ze = __fmaf_rn(zv[j], c[j], ze);
    return __fmaf_rn(-2.0f, ze, __fadd_rn(z2, e2f[k]));
}

// prep (layout unchanged since R6, validated): e2f table + B fragments.
// B[k][n]: n=lane&15 (code), k=(lane>>4)*8+j. quad0: eh, quad1: el, quad2: eh,
// quad3: {e2h, e2l, 0x6}. Also zeroes the 64 loss slots.
__global__ void prep(const float* __restrict__ cb, float* __restrict__ e2f,
                     unsigned short* __restrict__ wsB,
                     float* __restrict__ loss_ws) {
    const int tid = blockIdx.x * 256 + threadIdx.x;
    if (tid < NLOSS) loss_ws[tid] = 0.0f;
    const int t    = tid >> 6;
    const int lane = tid & 63;
    const int quad = lane >> 4;
    const int colc = lane & 15;
    const int n    = t * 16 + colc;
    float row[DDIM];
    #pragma unroll
    for (int j = 0; j < DDIM; ++j) row[j] = cb[n * DDIM + j];
    const float e2 = np_sumsq8(row);
    if (quad == 3) e2f[n] = e2;

    unsigned short sh[8];
    #pragma unroll
    for (int j = 0; j < 8; ++j) {
        const unsigned short eh = f2bf(row[j]);
        const unsigned short el = f2bf(__fsub_rn(row[j], bf2f(eh)));
        sh[j] = (quad == 1) ? el : eh;
    }
    if (quad == 3) {
        const unsigned short e2h = f2bf(e2);
        const unsigned short e2l = f2bf(__fsub_rn(e2, bf2f(e2h)));
        sh[0] = e2h; sh[1] = e2l;
        #pragma unroll
        for (int j = 2; j < 8; ++j) sh[j] = 0;
    }
    unsigned short* dst = wsB + (size_t)(t * 64 + lane) * 8;
    #pragma unroll
    for (int j = 0; j < 8; ++j) dst[j] = sh[j];
}

__global__ __launch_bounds__(BLK, 2) void vq_main(
    const float* __restrict__ z, const float* __restrict__ cb,
    const float* __restrict__ e2f, const unsigned short* __restrict__ wsB,
    float* __restrict__ out_zq, float* __restrict__ loss_ws,
    float* __restrict__ out_idx)
{
    __shared__ int            ccnt[PPB];               // 2 KB
    __shared__ unsigned short clist[PPB][CMAX];        // 4 KB
    __shared__ float          wsum[NWAVES];

    const int tid  = threadIdx.x;
    const int wave = tid >> 6;
    const int lane = tid & 63;
    const int quad = lane >> 4;
    const int col  = lane & 15;

    // ccnt slots are wave-private (writers = pushers in same wave; LDS-pipe
    // program order covers init -> atomics -> reads) -> no block barrier.
    ccnt[tid]       = 0;
    ccnt[tid + BLK] = 0;

    // two points per thread; both fully coalesced (block never straddles b)
    const int base = blockIdx.x * PPB;
    const int n0 = base + tid;
    const int n1 = n0 + BLK;
    const int b0 = n0 >> 16, s0 = n0 & 65535;
    const int b1 = n1 >> 16, s1 = n1 & 65535;
    const float* zp0 = z + (size_t)b0 * B_STRIDE + s0;
    const float* zp1 = z + (size_t)b1 * B_STRIDE + s1;
    float zva[DDIM], zvb[DDIM];
    #pragma unroll
    for (int j = 0; j < DDIM; ++j) {
        zva[j] = zp0[(size_t)j * CH_STRIDE];
        zvb[j] = zp1[(size_t)j * CH_STRIDE];
    }
    const float z2a = np_sumsq8(zva);
    const float z2b = np_sumsq8(zvb);

    // wave-wide z2 max over BOTH sets -> eps (>= per-set eps => guarantee holds)
    float zmax = fmaxf(z2a, z2b);
    #pragma unroll
    for (int mk = 1; mk <= 32; mk <<= 1) zmax = fmaxf(zmax, __shfl_xor(zmax, mk, 64));
    const float eps = zmax * 6e-7f + 3e-6f;

    // pre-pack A-material per set: lo16 = bf16(-2*zh), hi16 = bf16(-2*zl)
    unsigned pka[8], pkb[8];
    #pragma unroll
    for (int j = 0; j < 8; ++j) {
        {
            const unsigned short hh = f2bf(zva[j]);
            const float zh = bf2f(hh);
            const float zl = __fsub_rn(zva[j], zh);       // exact
            const unsigned short ah = f2bf(-2.0f * zh);   // exact
            const unsigned short al = f2bf(-2.0f * zl);
            pka[j] = (unsigned)ah | ((unsigned)al << 16);
        }
        {
            const unsigned short hh = f2bf(zvb[j]);
            const float zh = bf2f(hh);
            const float zl = __fsub_rn(zvb[j], zh);
            const unsigned short ah = f2bf(-2.0f * zh);
            const unsigned short al = f2bf(-2.0f * zl);
            pkb[j] = (unsigned)ah | ((unsigned)al << 16);
        }
    }

    // afrag_q at lane (col,quad): A[m=col][k=quad*8+j] from owner lane Q*16+col.
    // quad0/1: -2zh, quad2: -2zl, quad3: {1,1,0..} (validated)
    bf8 af0a, af1a, af2a, af3a, af0b, af1b, af2b, af3b;
#define MK_AFRAG(AF, Q, PK)                                                    \
    {                                                                          \
        const int srcl = (Q)*16 + col;                                         \
        _Pragma("unroll")                                                      \
        for (int j = 0; j < 8; ++j) {                                          \
            const unsigned w = (unsigned)__shfl((int)PK[j], srcl, 64);         \
            const unsigned us = (quad == 2) ? (w >> 16) : (w & 0xFFFFu);       \
            AF[j] = (short)us;                                                 \
        }                                                                      \
        if (quad == 3) AF = (bf8){(short)0x3F80, (short)0x3F80, 0, 0, 0, 0, 0, 0}; \
    }
    MK_AFRAG(af0a, 0, pka) MK_AFRAG(af1a, 1, pka)
    MK_AFRAG(af2a, 2, pka) MK_AFRAG(af3a, 3, pka)
    MK_AFRAG(af0b, 0, pkb) MK_AFRAG(af1b, 1, pkb)
    MK_AFRAG(af2b, 2, pkb) MK_AFRAG(af3b, 3, pkb)

    // B fragments from global: 32 KB table, L1/L2-hot; ONE load per tile now
    // feeds 8 independent MFMAs + 32 independent mins (the ILP lever).
    const bf8* __restrict__ Bp = (const bf8*)wsB;

    // ---- pass 1: approx min per point, both sets ----
    f4 mA0 = (f4){FLT_BIG, FLT_BIG, FLT_BIG, FLT_BIG};
    f4 mA1 = mA0, mA2 = mA0, mA3 = mA0;
    f4 mB0 = mA0, mB1 = mA0, mB2 = mA0, mB3 = mA0;
    #pragma unroll 2
    for (int t = 0; t < NTILES; ++t) {
        const bf8 bfrag = Bp[t * 64 + lane];
        f4 zero = (f4){0.0f, 0.0f, 0.0f, 0.0f};
        const f4 dA0 = __builtin_amdgcn_mfma_f32_16x16x32_bf16(af0a, bfrag, zero, 0, 0, 0);
        const f4 dA1 = __builtin_amdgcn_mfma_f32_16x16x32_bf16(af1a, bfrag, zero, 0, 0, 0);
        const f4 dA2 = __builtin_amdgcn_mfma_f32_16x16x32_bf16(af2a, bfrag, zero, 0, 0, 0);
        const f4 dA3 = __builtin_amdgcn_mfma_f32_16x16x32_bf16(af3a, bfrag, zero, 0, 0, 0);
        const f4 dB0 = __builtin_amdgcn_mfma_f32_16x16x32_bf16(af0b, bfrag, zero, 0, 0, 0);
        const f4 dB1 = __builtin_amdgcn_mfma_f32_16x16x32_bf16(af1b, bfrag, zero, 0, 0, 0);
        const f4 dB2 = __builtin_amdgcn_mfma_f32_16x16x32_bf16(af2b, bfrag, zero, 0, 0, 0);
        const f4 dB3 = __builtin_amdgcn_mfma_f32_16x16x32_bf16(af3b, bfrag, zero, 0, 0, 0);
        #pragma unroll
        for (int r = 0; r < 4; ++r) {
            mA0[r] = fminf(mA0[r], dA0[r]); mA1[r] = fminf(mA1[r], dA1[r]);
            mA2[r] = fminf(mA2[r], dA2[r]); mA3[r] = fminf(mA3[r], dA3[r]);
            mB0[r] = fminf(mB0[r], dB0[r]); mB1[r] = fminf(mB1[r], dB1[r]);
            mB2[r] = fminf(mB2[r], dB2[r]); mB3[r] = fminf(mB3[r], dB3[r]);
        }
    }
    // min across the 16 cols (xor bits 0..3); 8 interleaved chains
    #pragma unroll
    for (int mk = 1; mk <= 8; mk <<= 1) {
        #pragma unroll
        for (int r = 0; r < 4; ++r) {
            mA0[r] = fminf(mA0[r], __shfl_xor(mA0[r], mk, 64));
            mA1[r] = fminf(mA1[r], __shfl_xor(mA1[r], mk, 64));
            mA2[r] = fminf(mA2[r], __shfl_xor(mA2[r], mk, 64));
            mA3[r] = fminf(mA3[r], __shfl_xor(mA3[r], mk, 64));
            mB0[r] = fminf(mB0[r], __shfl_xor(mB0[r], mk, 64));
            mB1[r] = fminf(mB1[r], __shfl_xor(mB1[r], mk, 64));
            mB2[r] = fminf(mB2[r], __shfl_xor(mB2[r], mk, 64));
            mB3[r] = fminf(mB3[r], __shfl_xor(mB3[r], mk, 64));
        }
    }
    #pragma unroll
    for (int r = 0; r < 4; ++r) {
        mA0[r] += eps; mA1[r] += eps; mA2[r] += eps; mA3[r] += eps;
        mB0[r] += eps; mB1[r] += eps; mB2[r] += eps; mB3[r] += eps;
    }

    // ---- pass 2: identical accs; predicated push (rarely taken) ----
    // slots: setA = wave*64 + Q*16 + quad*4 + r, setB = BLK + same
    const int pb0 = wave * 64 + quad * 4;
    const int pb1 = BLK + pb0;
    #pragma unroll 2
    for (int t = 0; t < NTILES; ++t) {
        const bf8 bfrag = Bp[t * 64 + lane];
        f4 zero = (f4){0.0f, 0.0f, 0.0f, 0.0f};
        const f4 dA0 = __builtin_amdgcn_mfma_f32_16x16x32_bf16(af0a, bfrag, zero, 0, 0, 0);
        const f4 dA1 = __builtin_amdgcn_mfma_f32_16x16x32_bf16(af1a, bfrag, zero, 0, 0, 0);
        const f4 dA2 = __builtin_amdgcn_mfma_f32_16x16x32_bf16(af2a, bfrag, zero, 0, 0, 0);
        const f4 dA3 = __builtin_amdgcn_mfma_f32_16x16x32_bf16(af3a, bfrag, zero, 0, 0, 0);
        const f4 dB0 = __builtin_amdgcn_mfma_f32_16x16x32_bf16(af0b, bfrag, zero, 0, 0, 0);
        const f4 dB1 = __builtin_amdgcn_mfma_f32_16x16x32_bf16(af1b, bfrag, zero, 0, 0, 0);
        const f4 dB2 = __builtin_amdgcn_mfma_f32_16x16x32_bf16(af2b, bfrag, zero, 0, 0, 0);
        const f4 dB3 = __builtin_amdgcn_mfma_f32_16x16x32_bf16(af3b, bfrag, zero, 0, 0, 0);
        const unsigned short code = (unsigned short)(t * 16 + col);
#define PUSH(AQ, MQ, Q, PB)                                                    \
    {                                                                          \
        const bool c0 = AQ[0] <= MQ[0], c1 = AQ[1] <= MQ[1];                   \
        const bool c2 = AQ[2] <= MQ[2], c3 = AQ[3] <= MQ[3];                   \
        if (c0 | c1 | c2 | c3) {                                               \
            const int pt = (PB) + (Q)*16;                                      \
            if (c0) { int p = atomicAdd(&ccnt[pt + 0], 1); if (p < CMAX) clist[pt + 0][p] = code; } \
            if (c1) { int p = atomicAdd(&ccnt[pt + 1], 1); if (p < CMAX) clist[pt + 1][p] = code; } \
            if (c2) { int p = atomicAdd(&ccnt[pt + 2], 1); if (p < CMAX) clist[pt + 2][p] = code; } \
            if (c3) { int p = atomicAdd(&ccnt[pt + 3], 1); if (p < CMAX) clist[pt + 3][p] = code; } \
        }                                                                      \
    }
        PUSH(dA0, mA0, 0, pb0) PUSH(dA1, mA1, 1, pb0)
        PUSH(dA2, mA2, 2, pb0) PUSH(dA3, mA3, 3, pb0)
        PUSH(dB0, mB0, 0, pb1) PUSH(dB1, mB1, 1, pb1)
        PUSH(dB2, mB2, 2, pb1) PUSH(dB3, mB3, 3, pb1)
    }

    // ccnt/clist slots for this wave's 128 points are wave-private -> no
    // block barrier; drain this wave's LDS ops (writes + atomics + shuffles).
    asm volatile("s_waitcnt lgkmcnt(0)" ::: "memory");

    // ---- phase C: resolve both points np-exactly ----
    auto resolve = [&](int slot, const float* zv, float z2) -> int {
        const int cnt = ccnt[slot];
        int bidx;
        if (cnt == 1) {
            // eps guarantee: candidate set contains np's argmin; singleton => done
            bidx = clist[slot][0];
        } else if (cnt <= CMAX) {
            float best = FLT_BIG; bidx = 0;
            for (int i = 0; i < cnt; ++i) {
                const int k = clist[slot][i];
                const float d = np_dist(cb, e2f, k, zv, z2);
                // order-independent np first-min
                if (d < best || (d == best && k < bidx)) { best = d; bidx = k; }
            }
        } else {  // overflow fallback: full exact scan (correctness net)
            float best = FLT_BIG; bidx = 0;
            for (int k = 0; k < KCODES; ++k) {
                const float d = np_dist(cb, e2f, k, zv, z2);
                if (d < best) { best = d; bidx = k; }
            }
        }
        return bidx;
    };

    const int bidx0 = resolve(tid, zva, z2a);
    const int bidx1 = resolve(tid + BLK, zvb, z2b);
    out_idx[n0] = (float)bidx0;
    out_idx[n1] = (float)bidx1;

    float lsum = 0.0f;
    {
        const float* cw = cb + (size_t)bidx0 * DDIM;
        float* op = out_zq + (size_t)b0 * B_STRIDE + s0;
        #pragma unroll
        for (int j = 0; j < DDIM; ++j) {
            const float zq = cw[j];
            const float t  = __fsub_rn(zq, zva[j]);           // np: z_q - z
            op[(size_t)j * CH_STRIDE] = __fadd_rn(zva[j], t); // np: z + (z_q - z)
            lsum = __fmaf_rn(t, t, lsum);                     // loss (2% tol)
        }
    }
    {
        const float* cw = cb + (size_t)bidx1 * DDIM;
        float* op = out_zq + (size_t)b1 * B_STRIDE + s1;
        #pragma unroll
        for (int j = 0; j < DDIM; ++j) {
            const float zq = cw[j];
            const float t  = __fsub_rn(zq, zvb[j]);
            op[(size_t)j * CH_STRIDE] = __fadd_rn(zvb[j], t);
            lsum = __fmaf_rn(t, t, lsum);
        }
    }

    // loss: wave butterfly -> LDS wsum -> one atomic per BLOCK, spread over
    // 64 slots (1024 blocks / 64 slots = 16 adds/slot; no drain tail)
    #pragma unroll
    for (int off = 32; off > 0; off >>= 1) lsum += __shfl_down(lsum, off, 64);
    if (lane == 0) wsum[wave] = lsum;
    __syncthreads();
    if (tid == 0) {
        float bs = 0.0f;
        #pragma unroll
        for (int w = 0; w < NWAVES; ++w) bs += wsum[w];
        atomicAdd(&loss_ws[blockIdx.x & (NLOSS - 1)], bs);
    }
}

// 1-wave finisher: sums the 64 loss slots. Own dispatch => cross-XCD
// coherence for the atomics above; no fences needed.
__global__ void loss_fin(const float* __restrict__ loss_ws,
                         float* __restrict__ out_loss) {
    const int lane = threadIdx.x;
    float v = loss_ws[lane];
    #pragma unroll
    for (int off = 32; off > 0; off >>= 1) v += __shfl_down(v, off, 64);
    // vq_loss = codebk + BETA*commit = 1.25 * mean((z_q - z)^2)
    if (lane == 0) *out_loss = v * (1.25f / 4194304.0f);
}

extern "C" void kernel_launch(void* const* d_in, const int* in_sizes, int n_in,
                              void* d_out, int out_size, void* d_ws, size_t ws_size,
                              hipStream_t stream) {
    const float* z  = (const float*)d_in[0];
    const float* cb = (const float*)d_in[1];
    float* out      = (float*)d_out;
    float* out_zq   = out;                    // 4194304 elems
    float* out_loss = out + 4194304;          // 1 elem
    float* out_idx  = out + 4194305;          // 524288 elems (as float values)
    float* e2f            = (float*)d_ws;                           // 512 f32
    unsigned short* wsB   = (unsigned short*)((char*)d_ws + 2048);  // 32KB frags
    float* loss_ws        = (float*)((char*)d_ws + 2048 + 32768);   // 64 f32

    prep<<<8, 256, 0, stream>>>(cb, e2f, wsB, loss_ws);
    vq_main<<<NPTS / PPB, BLK, 0, stream>>>(z, cb, e2f, wsB,
                                            out_zq, loss_ws, out_idx);
    loss_fin<<<1, 64, 0, stream>>>(loss_ws, out_loss);
}

// Round 3
// 127.786 us; speedup vs baseline: 1.1586x; 1.1586x over previous
//
#include <hip/hip_runtime.h>

// VQ quantizer: z [8,8,16,64,64] f32, codebook [512,8] f32
// outputs concat: z_q_st (4194304 f32) | vq_loss (1 f32) | idx (524288 f32-valued)
//
// R17 = R14 structure (LDS-B, 512thr, 1pt/thread) + register-liveness fix.
// R16 post-mortem: runtime == 53k-VALU-cycles / VALUBusy; VALUBusy = resident
// waves x per-wave density. Residency (not ILP) is the lever. R14's unroll-4
// kept ~16 f4 MFMA results live (~64 acc regs) -> total VGPR+AGPR ~160 ->
// 3 waves/SIMD (Occ 35%). This version:
//  - quad-pair compute with IMMEDIATE min3 consumption: <=2 f4 MFMA results
//    live at any time; explicit 1-deep LDS prefetch rotate instead of
//    unroll-based pipelining. Target total <=128 regs -> 4 waves/SIMD.
//  - pass1 min via v_min3 (nested fminf fuses): -256 VALU/wave.
//  - pass2 paired threshold test (logically identical candidate set;
//    individual re-test inside rare branch).
//  - CMAX 4->8: divergent 512-iter full-scan fallback ~never taken.
// Numerics bit-identical to validated R6-R14 chain (same MFMA inputs, min is
// order-independent, same eps/thresholds/candidates, same phase-C).

#define NPTS      524288      // 8*16*64*64
#define KCODES    512
#define DDIM      8
#define CH_STRIDE 65536       // T*H*W
#define B_STRIDE  524288      // D*T*H*W
#define BLK       512
#define NWAVES    8
#define NTILES    32          // 512 codes / 16
#define CMAX      8
#define NLOSS     64          // loss accumulation slots
#define FLT_BIG   3.402823466e+38f

typedef short bf8 __attribute__((ext_vector_type(8)));   // 8 bf16 (4 VGPRs)
typedef float f4  __attribute__((ext_vector_type(4)));   // fp32 accum

__device__ __forceinline__ unsigned short f2bf(float f) {   // RNE f32->bf16
    unsigned u = __float_as_uint(f);
    unsigned r = u + 0x7fffu + ((u >> 16) & 1u);
    return (unsigned short)(r >> 16);
}
__device__ __forceinline__ float bf2f(unsigned short h) {
    return __uint_as_float(((unsigned)h) << 16);
}

// numpy pairwise-sum tree for n=8 (validated absmax 0, R1-R16)
__device__ __forceinline__ float np_sumsq8(const float* x) {
    float p0 = __fmul_rn(x[0], x[0]);
    float p1 = __fmul_rn(x[1], x[1]);
    float p2 = __fmul_rn(x[2], x[2]);
    float p3 = __fmul_rn(x[3], x[3]);
    float p4 = __fmul_rn(x[4], x[4]);
    float p5 = __fmul_rn(x[5], x[5]);
    float p6 = __fmul_rn(x[6], x[6]);
    float p7 = __fmul_rn(x[7], x[7]);
    return __fadd_rn(__fadd_rn(__fadd_rn(p0, p1), __fadd_rn(p2, p3)),
                     __fadd_rn(__fadd_rn(p4, p5), __fadd_rn(p6, p7)));
}

// np-exact distance (identical rounding chain, absmax-0 validated)
__device__ __forceinline__ float np_dist(const float* __restrict__ cb,
                                         const float* __restrict__ e2f,
                                         int k, const float* zv, float z2) {
    const float* c = cb + (size_t)k * DDIM;
    float ze = 0.0f;
    #pragma unroll
    for (int j = 0; j < DDIM; ++j) ze = __fmaf_rn(zv[j], c[j], ze);
    return __fmaf_rn(-2.0f, ze, __fadd_rn(z2, e2f[k]));
}

// prep (layout unchanged since R6, validated): e2f table + B fragments.
// B[k][n]: n=lane&15 (code), k=(lane>>4)*8+j. quad0: eh, quad1: el, quad2: eh,
// quad3: {e2h, e2l, 0x6}. Also zeroes the 64 loss slots.
__global__ void prep(const float* __restrict__ cb, float* __restrict__ e2f,
                     unsigned short* __restrict__ wsB,
                     float* __restrict__ loss_ws) {
    const int tid = blockIdx.x * 256 + threadIdx.x;
    if (tid < NLOSS) loss_ws[tid] = 0.0f;
    const int t    = tid >> 6;
    const int lane = tid & 63;
    const int quad = lane >> 4;
    const int colc = lane & 15;
    const int n    = t * 16 + colc;
    float row[DDIM];
    #pragma unroll
    for (int j = 0; j < DDIM; ++j) row[j] = cb[n * DDIM + j];
    const float e2 = np_sumsq8(row);
    if (quad == 3) e2f[n] = e2;

    unsigned short sh[8];
    #pragma unroll
    for (int j = 0; j < 8; ++j) {
        const unsigned short eh = f2bf(row[j]);
        const unsigned short el = f2bf(__fsub_rn(row[j], bf2f(eh)));
        sh[j] = (quad == 1) ? el : eh;
    }
    if (quad == 3) {
        const unsigned short e2h = f2bf(e2);
        const unsigned short e2l = f2bf(__fsub_rn(e2, bf2f(e2h)));
        sh[0] = e2h; sh[1] = e2l;
        #pragma unroll
        for (int j = 2; j < 8; ++j) sh[j] = 0;
    }
    unsigned short* dst = wsB + (size_t)(t * 64 + lane) * 8;
    #pragma unroll
    for (int j = 0; j < 8; ++j) dst[j] = sh[j];
}

__global__ __launch_bounds__(BLK, 4) void vq_main(
    const float* __restrict__ z, const float* __restrict__ cb,
    const float* __restrict__ e2f, const unsigned short* __restrict__ wsB,
    float* __restrict__ out_zq, float* __restrict__ loss_ws,
    float* __restrict__ out_idx)
{
    __shared__ unsigned short ldsB[NTILES * 64 * 8];   // 32 KB
    __shared__ int            ccnt[BLK];               // 2 KB
    __shared__ unsigned short clist[BLK][CMAX];        // 8 KB
    __shared__ float          wsum[NWAVES];

    const int tid  = threadIdx.x;
    const int wave = tid >> 6;
    const int lane = tid & 63;
    const int quad = lane >> 4;
    const int col  = lane & 15;

    // z loads first: HBM latency overlaps staging + barrier.
    const int n = blockIdx.x * BLK + tid;
    const int b = n >> 16;
    const int s = n & 65535;
    const float* zp = z + (size_t)b * B_STRIDE + s;
    float zv[DDIM];
    #pragma unroll
    for (int j = 0; j < DDIM; ++j) zv[j] = zp[(size_t)j * CH_STRIDE];

    // stage B fragments global -> LDS (32 KB, coalesced uint4, 4 iters @512thr)
    {
        const uint4* src = (const uint4*)wsB;
        uint4* dst = (uint4*)ldsB;
        #pragma unroll
        for (int q = 0; q < 4; ++q)
            dst[tid + q * BLK] = src[tid + q * BLK];
    }
    ccnt[tid] = 0;

    const float z2 = np_sumsq8(zv);

    // wave-wide z2 max -> eps (validated constants)
    float zmax = z2;
    #pragma unroll
    for (int mk = 1; mk <= 32; mk <<= 1) zmax = fmaxf(zmax, __shfl_xor(zmax, mk, 64));
    const float eps = zmax * 6e-7f + 3e-6f;

    // pre-pack own point's A-material: lo16 = bf16(-2*zh), hi16 = bf16(-2*zl)
    unsigned pkz[8];
    #pragma unroll
    for (int j = 0; j < 8; ++j) {
        const unsigned short hh = f2bf(zv[j]);
        const float zh = bf2f(hh);
        const float zl = __fsub_rn(zv[j], zh);        // exact
        const unsigned short ah = f2bf(-2.0f * zh);   // exact
        const unsigned short al = f2bf(-2.0f * zl);
        pkz[j] = (unsigned)ah | ((unsigned)al << 16);
    }

    // afrag_q at lane (col,quad): A[m=col][k=quad*8+j] from owner lane q*16+col.
    // quad0/1: -2zh, quad2: -2zl, quad3: {1,1,0..} (validated)
    bf8 af0, af1, af2, af3;
#define MK_AFRAG(AF, Q)                                                        \
    {                                                                          \
        const int srcl = (Q)*16 + col;                                         \
        _Pragma("unroll")                                                      \
        for (int j = 0; j < 8; ++j) {                                          \
            const unsigned w = (unsigned)__shfl((int)pkz[j], srcl, 64);        \
            const unsigned us = (quad == 2) ? (w >> 16) : (w & 0xFFFFu);       \
            AF[j] = (short)us;                                                 \
        }                                                                      \
        if (quad == 3) AF = (bf8){(short)0x3F80, (short)0x3F80, 0, 0, 0, 0, 0, 0}; \
    }
    MK_AFRAG(af0, 0) MK_AFRAG(af1, 1) MK_AFRAG(af2, 2) MK_AFRAG(af3, 3)

    __syncthreads();   // ldsB staged by all waves

    const bf8* __restrict__ Bp = (const bf8*)ldsB;   // ds_read_b128 per tile
    const f4 zero = (f4){0.0f, 0.0f, 0.0f, 0.0f};

    // ---- pass 1: approx min per point; tile pairs, immediate min3 consume.
    // Liveness: only dA,dB (2 f4) + rotate regs live -> total regs <=128.
    f4 mn0 = (f4){FLT_BIG, FLT_BIG, FLT_BIG, FLT_BIG};
    f4 mn1 = mn0, mn2 = mn0, mn3 = mn0;
    {
        bf8 bA = Bp[lane];
        bf8 bB = Bp[64 + lane];
        #pragma unroll 1
        for (int t = 0; t < NTILES; t += 2) {
            const bf8 cA = bA, cB = bB;
            bA = Bp[(((t + 2) & 31) * 64) + lane];   // 1-deep prefetch rotate
            bB = Bp[(((t + 3) & 31) * 64) + lane];
            f4 dA, dB;
#define P1Q(AF, MN)                                                            \
            dA = __builtin_amdgcn_mfma_f32_16x16x32_bf16(AF, cA, zero, 0, 0, 0); \
            dB = __builtin_amdgcn_mfma_f32_16x16x32_bf16(AF, cB, zero, 0, 0, 0); \
            _Pragma("unroll")                                                  \
            for (int r = 0; r < 4; ++r)                                        \
                MN[r] = fminf(fminf(MN[r], dA[r]), dB[r]);   /* v_min3 */
            P1Q(af0, mn0) P1Q(af1, mn1) P1Q(af2, mn2) P1Q(af3, mn3)
#undef P1Q
        }
    }
    // min across the 16 cols (xor bits 0..3), then add eps -> thresholds
    #pragma unroll
    for (int mk = 1; mk <= 8; mk <<= 1) {
        #pragma unroll
        for (int r = 0; r < 4; ++r) {
            mn0[r] = fminf(mn0[r], __shfl_xor(mn0[r], mk, 64));
            mn1[r] = fminf(mn1[r], __shfl_xor(mn1[r], mk, 64));
            mn2[r] = fminf(mn2[r], __shfl_xor(mn2[r], mk, 64));
            mn3[r] = fminf(mn3[r], __shfl_xor(mn3[r], mk, 64));
        }
    }
    #pragma unroll
    for (int r = 0; r < 4; ++r) {
        mn0[r] += eps; mn1[r] += eps; mn2[r] += eps; mn3[r] += eps;
    }

    // ---- pass 2: identical accs; paired threshold test, rare pushes ----
    // C layout: point-in-block = wave*64 + Q*16 + quad*4 + r, code = t*16 + col
    const int pbase = wave * 64 + quad * 4;
#define PUSHC(SLOT, CODE)                                                      \
    { int p = atomicAdd(&ccnt[SLOT], 1); if (p < CMAX) clist[SLOT][p] = (unsigned short)(CODE); }
    {
        bf8 bA = Bp[lane];
        bf8 bB = Bp[64 + lane];
        #pragma unroll 1
        for (int t = 0; t < NTILES; t += 2) {
            const bf8 cA = bA, cB = bB;
            bA = Bp[(((t + 2) & 31) * 64) + lane];
            bB = Bp[(((t + 3) & 31) * 64) + lane];
            const int codeA = t * 16 + col;
            const int codeB = codeA + 16;
            f4 dA, dB;
#define P2Q(AF, MN, Q)                                                         \
            dA = __builtin_amdgcn_mfma_f32_16x16x32_bf16(AF, cA, zero, 0, 0, 0); \
            dB = __builtin_amdgcn_mfma_f32_16x16x32_bf16(AF, cB, zero, 0, 0, 0); \
            {                                                                  \
                const bool h0 = fminf(dA[0], dB[0]) <= MN[0];                  \
                const bool h1 = fminf(dA[1], dB[1]) <= MN[1];                  \
                const bool h2 = fminf(dA[2], dB[2]) <= MN[2];                  \
                const bool h3 = fminf(dA[3], dB[3]) <= MN[3];                  \
                if (h0 | h1 | h2 | h3) {                                       \
                    const int pt = pbase + (Q)*16;                             \
                    if (h0) { if (dA[0] <= MN[0]) PUSHC(pt + 0, codeA)         \
                              if (dB[0] <= MN[0]) PUSHC(pt + 0, codeB) }       \
                    if (h1) { if (dA[1] <= MN[1]) PUSHC(pt + 1, codeA)         \
                              if (dB[1] <= MN[1]) PUSHC(pt + 1, codeB) }       \
                    if (h2) { if (dA[2] <= MN[2]) PUSHC(pt + 2, codeA)         \
                              if (dB[2] <= MN[2]) PUSHC(pt + 2, codeB) }       \
                    if (h3) { if (dA[3] <= MN[3]) PUSHC(pt + 3, codeA)         \
                              if (dB[3] <= MN[3]) PUSHC(pt + 3, codeB) }       \
                }                                                              \
            }
            P2Q(af0, mn0, 0) P2Q(af1, mn1, 1) P2Q(af2, mn2, 2) P2Q(af3, mn3, 3)
#undef P2Q
        }
    }

    // ccnt/clist for this wave's 64 points is written and read ONLY by this
    // wave -> no block barrier; drain this wave's LDS ops (writes + atomics).
    asm volatile("s_waitcnt lgkmcnt(0)" ::: "memory");

    // ---- phase C: every lane resolves its own point np-exactly ----
    const int cnt = ccnt[tid];
    int bidx;
    if (cnt == 1) {
        // eps guarantee: candidate set contains np's argmin; singleton => done
        bidx = clist[tid][0];
    } else if (cnt <= CMAX) {
        float best = FLT_BIG; bidx = 0;
        for (int i = 0; i < cnt; ++i) {
            const int k = clist[tid][i];
            const float d = np_dist(cb, e2f, k, zv, z2);
            // order-independent np first-min
            if (d < best || (d == best && k < bidx)) { best = d; bidx = k; }
        }
    } else {  // overflow fallback: full exact scan (correctness net, ~never)
        float best = FLT_BIG; bidx = 0;
        for (int k = 0; k < KCODES; ++k) {
            const float d = np_dist(cb, e2f, k, zv, z2);
            if (d < best) { best = d; bidx = k; }
        }
    }
    out_idx[n] = (float)bidx;

    const float* cw = cb + (size_t)bidx * DDIM;
    float* op = out_zq + (size_t)b * B_STRIDE + s;
    float lsum = 0.0f;
    #pragma unroll
    for (int j = 0; j < DDIM; ++j) {
        const float zq = cw[j];
        const float t  = __fsub_rn(zq, zv[j]);            // np: z_q - z
        op[(size_t)j * CH_STRIDE] = __fadd_rn(zv[j], t);  // np: z + (z_q - z)
        lsum = __fmaf_rn(t, t, lsum);                     // loss (2% tol)
    }

    // loss: wave butterfly -> LDS wsum -> one atomic per BLOCK, spread over
    // 64 slots (1024 blocks / 64 slots = 16 adds/slot; no drain tail)
    #pragma unroll
    for (int off = 32; off > 0; off >>= 1) lsum += __shfl_down(lsum, off, 64);
    if (lane == 0) wsum[wave] = lsum;
    __syncthreads();
    if (tid == 0) {
        float bs = 0.0f;
        #pragma unroll
        for (int w = 0; w < NWAVES; ++w) bs += wsum[w];
        atomicAdd(&loss_ws[blockIdx.x & (NLOSS - 1)], bs);
    }
}

// 1-wave finisher: sums the 64 loss slots. Own dispatch => cross-XCD
// coherence for the atomics above; no fences needed.
__global__ void loss_fin(const float* __restrict__ loss_ws,
                         float* __restrict__ out_loss) {
    const int lane = threadIdx.x;
    float v = loss_ws[lane];
    #pragma unroll
    for (int off = 32; off > 0; off >>= 1) v += __shfl_down(v, off, 64);
    // vq_loss = codebk + BETA*commit = 1.25 * mean((z_q - z)^2)
    if (lane == 0) *out_loss = v * (1.25f / 4194304.0f);
}

extern "C" void kernel_launch(void* const* d_in, const int* in_sizes, int n_in,
                              void* d_out, int out_size, void* d_ws, size_t ws_size,
                              hipStream_t stream) {
    const float* z  = (const float*)d_in[0];
    const float* cb = (const float*)d_in[1];
    float* out      = (float*)d_out;
    float* out_zq   = out;                    // 4194304 elems
    float* out_loss = out + 4194304;          // 1 elem
    float* out_idx  = out + 4194305;          // 524288 elems (as float values)
    float* e2f            = (float*)d_ws;                           // 512 f32
    unsigned short* wsB   = (unsigned short*)((char*)d_ws + 2048);  // 32KB frags
    float* loss_ws        = (float*)((char*)d_ws + 2048 + 32768);   // 64 f32

    prep<<<8, 256, 0, stream>>>(cb, e2f, wsB, loss_ws);
    vq_main<<<NPTS / BLK, BLK, 0, stream>>>(z, cb, e2f, wsB,
                                            out_zq, loss_ws, out_idx);
    loss_fin<<<1, 64, 0, stream>>>(loss_ws, out_loss);
}